// Round 2
// baseline (184.868 us; speedup 1.0000x reference)
//
#include <hip/hip_runtime.h>

// PeerNet: out = relu-MLP with per-feature kNN-mean (k=6, 1D) in the middle.
// B=4096, D=1024, H1=128, H2=64, O=2. All fp32.

#define NB   4096
#define DIN  1024
#define NH1  128
#define NH2  64

// ---------------------------------------------------------------------------
// GEMM1: h1T[128][4096] = relu(x[4096][1024] @ W1[128][1024]^T + b1)
// BM=16, BN=128(=N), BK=16, 256 threads.
// Thread tile: 2 rows x 4 cols = 8 outputs/thread (16*128/256).
//   tr = tid>>5 in [0,8)  -> rows 2*tr, 2*tr+1
//   tc = tid&31 in [0,32) -> cols 4*tc .. 4*tc+3   (32*4 = 128, full cover)
// Epilogue bounces the 16x128 tile through LDS to store h1 TRANSPOSED
// coalesced (64B segments along m).
// ---------------------------------------------------------------------------
__global__ __launch_bounds__(256) void gemm1_kernel(const float* __restrict__ A,
                                                    const float* __restrict__ Bw,
                                                    const float* __restrict__ bias,
                                                    float* __restrict__ CT)
{
    const int K = DIN;   // 1024
    const int M = NB;    // 4096
    __shared__ float As[16 * 18];    // [k][m], pad 18
    __shared__ float Bs[16 * 132];   // [k][n], pad 132
    const int tid = threadIdx.x;
    const int m0  = blockIdx.x * 16;
    const int tr  = tid >> 5;        // 0..7  -> rows 2*tr, 2*tr+1
    const int tc  = tid & 31;        // 0..31 -> cols 4*tc..4*tc+3
    const int am  = tid >> 4, ak = tid & 15;
    const int bn  = tid >> 2, bk = (tid & 3) << 2;

    float acc[2][4];
#pragma unroll
    for (int i = 0; i < 2; ++i)
#pragma unroll
        for (int j = 0; j < 4; ++j) acc[i][j] = 0.f;

    for (int k0 = 0; k0 < K; k0 += 16) {
        As[ak * 18 + am] = A[(m0 + am) * K + k0 + ak];
        const float4 v0 = *(const float4*)&Bw[bn * K + k0 + bk];
        const float4 v1 = *(const float4*)&Bw[(bn + 64) * K + k0 + bk];
        Bs[(bk + 0) * 132 + bn] = v0.x;
        Bs[(bk + 1) * 132 + bn] = v0.y;
        Bs[(bk + 2) * 132 + bn] = v0.z;
        Bs[(bk + 3) * 132 + bn] = v0.w;
        Bs[(bk + 0) * 132 + bn + 64] = v1.x;
        Bs[(bk + 1) * 132 + bn + 64] = v1.y;
        Bs[(bk + 2) * 132 + bn + 64] = v1.z;
        Bs[(bk + 3) * 132 + bn + 64] = v1.w;
        __syncthreads();
#pragma unroll
        for (int k = 0; k < 16; ++k) {
            const float2 a = *(const float2*)&As[k * 18 + 2 * tr];
            const float4 b = *(const float4*)&Bs[k * 132 + 4 * tc];
            acc[0][0] = fmaf(a.x, b.x, acc[0][0]);
            acc[0][1] = fmaf(a.x, b.y, acc[0][1]);
            acc[0][2] = fmaf(a.x, b.z, acc[0][2]);
            acc[0][3] = fmaf(a.x, b.w, acc[0][3]);
            acc[1][0] = fmaf(a.y, b.x, acc[1][0]);
            acc[1][1] = fmaf(a.y, b.y, acc[1][1]);
            acc[1][2] = fmaf(a.y, b.z, acc[1][2]);
            acc[1][3] = fmaf(a.y, b.w, acc[1][3]);
        }
        __syncthreads();
    }

    const float4 bb = *(const float4*)&bias[4 * tc];
#pragma unroll
    for (int mi = 0; mi < 2; ++mi) {
        acc[mi][0] = fmaxf(acc[mi][0] + bb.x, 0.f);
        acc[mi][1] = fmaxf(acc[mi][1] + bb.y, 0.f);
        acc[mi][2] = fmaxf(acc[mi][2] + bb.z, 0.f);
        acc[mi][3] = fmaxf(acc[mi][3] + bb.w, 0.f);
    }

    // bounce tile through Bs (reused as Ct[m][n], stride 132) for coalesced
    // transposed stores. Last loop iteration ended with __syncthreads().
#pragma unroll
    for (int mi = 0; mi < 2; ++mi) {
        const int m = 2 * tr + mi;
#pragma unroll
        for (int j = 0; j < 4; ++j)
            Bs[m * 132 + 4 * tc + j] = acc[mi][j];
    }
    __syncthreads();
#pragma unroll
    for (int it = 0; it < 8; ++it) {
        const int idx = it * 256 + tid;
        const int n = idx >> 4, m = idx & 15;
        CT[n * M + m0 + m] = Bs[m * 132 + n];
    }
}

// ---------------------------------------------------------------------------
// kNN-mean per feature column. One block per column (128 blocks, 1024 thr).
// Bitonic-sort the 4096 column values in LDS; per element: lower_bound its
// value, greedily take the 5 nearest of left/right neighbors in sorted
// order (k=6 incl. self), write mean to prtT[col][row].
// Tie semantics: equal distances only arise from duplicate values (relu
// zeros) -> selected VALUES identical to lax.top_k's choice.
// ---------------------------------------------------------------------------
__global__ __launch_bounds__(1024) void knn_kernel(const float* __restrict__ h1T,
                                                   float* __restrict__ prtT)
{
    __shared__ float s[NB];
    const int col = blockIdx.x;
    const float* __restrict__ colp = h1T + (size_t)col * NB;
#pragma unroll
    for (int p = 0; p < 4; ++p) s[threadIdx.x + p * 1024] = colp[threadIdx.x + p * 1024];
    __syncthreads();

    for (int k = 2; k <= NB; k <<= 1) {
        for (int j = k >> 1; j > 0; j >>= 1) {
#pragma unroll
            for (int p = 0; p < 4; ++p) {
                const int i   = threadIdx.x + p * 1024;
                const int ixj = i ^ j;
                if (ixj > i) {
                    const float a = s[i], b = s[ixj];
                    const bool up = ((i & k) == 0);
                    if ((a > b) == up) { s[i] = b; s[ixj] = a; }
                }
            }
            __syncthreads();
        }
    }

#pragma unroll
    for (int p = 0; p < 4; ++p) {
        const int e   = threadIdx.x + p * 1024;
        const float v = colp[e];
        // lower_bound: first index with s[idx] >= v (v is in the set)
        int lo = 0, hi = NB;
        while (lo < hi) {
            const int mid = (lo + hi) >> 1;
            if (s[mid] < v) lo = mid + 1; else hi = mid;
        }
        int l = lo, h = lo;
        float sum = v;  // self
#pragma unroll
        for (int it = 0; it < 5; ++it) {
            const int li = (l > 0) ? l - 1 : 0;
            const int ri = (h < NB - 1) ? h + 1 : NB - 1;
            const float sl = s[li];
            const float sr = s[ri];
            const float dl = (l > 0) ? (v - sl) : 1e30f;
            const float dr = (h < NB - 1) ? (sr - v) : 1e30f;
            if (dl <= dr) { sum += sl; l = li; }
            else          { sum += sr; h = ri; }
        }
        prtT[(size_t)col * NB + e] = sum * (1.0f / 6.0f);
    }
}

// ---------------------------------------------------------------------------
// Generic small GEMM: C[M][N] = relu(A[M][K] @ B[N][K]^T + bias)
// AT=true: A is stored transposed as A_T[K][M] (used for prtT input).
// BM=16, BN=64, BK=16, 256 threads, 4 outputs/thread.
// ---------------------------------------------------------------------------
template <bool AT>
__global__ __launch_bounds__(256) void gemm_small_kernel(const float* __restrict__ A,
                                                         const float* __restrict__ Bw,
                                                         const float* __restrict__ bias,
                                                         float* __restrict__ C,
                                                         int M, int N, int K)
{
    __shared__ float As[16 * 17];   // [k][m]
    __shared__ float Bs[16 * 68];   // [k][n]
    const int tid = threadIdx.x;
    const int m0 = blockIdx.x * 16;
    const int n0 = blockIdx.y * 64;
    const int r  = tid >> 4;
    const int c0 = (tid & 15) << 2;
    const int bn = tid >> 2, bk = (tid & 3) << 2;
    float acc[4] = {0.f, 0.f, 0.f, 0.f};

    for (int k0 = 0; k0 < K; k0 += 16) {
        if (AT) {
            As[(tid >> 4) * 17 + (tid & 15)] = A[(k0 + (tid >> 4)) * M + m0 + (tid & 15)];
        } else {
            As[(tid & 15) * 17 + (tid >> 4)] = A[(m0 + (tid >> 4)) * K + k0 + (tid & 15)];
        }
        const float4 v = *(const float4*)&Bw[(n0 + bn) * K + k0 + bk];
        Bs[(bk + 0) * 68 + bn] = v.x;
        Bs[(bk + 1) * 68 + bn] = v.y;
        Bs[(bk + 2) * 68 + bn] = v.z;
        Bs[(bk + 3) * 68 + bn] = v.w;
        __syncthreads();
#pragma unroll
        for (int k = 0; k < 16; ++k) {
            const float a  = As[k * 17 + r];
            const float4 b = *(const float4*)&Bs[k * 68 + c0];
            acc[0] = fmaf(a, b.x, acc[0]);
            acc[1] = fmaf(a, b.y, acc[1]);
            acc[2] = fmaf(a, b.z, acc[2]);
            acc[3] = fmaf(a, b.w, acc[3]);
        }
        __syncthreads();
    }
    const float4 bb = *(const float4*)&bias[n0 + c0];
    float4 o;
    o.x = fmaxf(acc[0] + bb.x, 0.f);
    o.y = fmaxf(acc[1] + bb.y, 0.f);
    o.z = fmaxf(acc[2] + bb.z, 0.f);
    o.w = fmaxf(acc[3] + bb.w, 0.f);
    *(float4*)&C[(size_t)(m0 + r) * N + n0 + c0] = o;
}

// ---------------------------------------------------------------------------
// Final: out[4096][2] = h2[4096][64] @ Wo[2][64]^T + bo  (no relu)
// ---------------------------------------------------------------------------
__global__ __launch_bounds__(256) void out_kernel(const float* __restrict__ h2v,
                                                  const float* __restrict__ Wo,
                                                  const float* __restrict__ bo,
                                                  float* __restrict__ out)
{
    const int row = blockIdx.x * 256 + threadIdx.x;
    const float* __restrict__ hp = h2v + row * NH2;
    float a0 = 0.f, a1 = 0.f;
#pragma unroll
    for (int k = 0; k < NH2; k += 4) {
        const float4 h  = *(const float4*)&hp[k];
        const float4 w0 = *(const float4*)&Wo[k];
        const float4 w1 = *(const float4*)&Wo[NH2 + k];
        a0 = fmaf(h.x, w0.x, a0); a0 = fmaf(h.y, w0.y, a0);
        a0 = fmaf(h.z, w0.z, a0); a0 = fmaf(h.w, w0.w, a0);
        a1 = fmaf(h.x, w1.x, a1); a1 = fmaf(h.y, w1.y, a1);
        a1 = fmaf(h.z, w1.z, a1); a1 = fmaf(h.w, w1.w, a1);
    }
    out[row * 2 + 0] = a0 + bo[0];
    out[row * 2 + 1] = a1 + bo[1];
}

extern "C" void kernel_launch(void* const* d_in, const int* in_sizes, int n_in,
                              void* d_out, int out_size, void* d_ws, size_t ws_size,
                              hipStream_t stream)
{
    const float* x   = (const float*)d_in[0];
    const float* W1  = (const float*)d_in[1];
    const float* b1  = (const float*)d_in[2];
    const float* Wpr = (const float*)d_in[3];
    const float* bpr = (const float*)d_in[4];
    const float* W2  = (const float*)d_in[5];
    const float* b2  = (const float*)d_in[6];
    const float* Wo  = (const float*)d_in[7];
    const float* bo  = (const float*)d_in[8];

    float* ws   = (float*)d_ws;
    float* h1T  = ws;                    // [128][4096]  2 MB
    float* prtT = ws + 1 * NB * NH1;     // [128][4096]  2 MB
    float* pr2  = ws + 2 * NB * NH1;     // [4096][128]  2 MB
    float* hh2  = ws + 3 * NB * NH1;     // [4096][64]   1 MB

    gemm1_kernel<<<dim3(NB / 16), 256, 0, stream>>>(x, W1, b1, h1T);
    knn_kernel<<<dim3(NH1), 1024, 0, stream>>>(h1T, prtT);
    gemm_small_kernel<true><<<dim3(NB / 16, NH1 / 64), 256, 0, stream>>>(
        prtT, Wpr, bpr, pr2, NB, NH1, NH1);
    gemm_small_kernel<false><<<dim3(NB / 16, NH2 / 64), 256, 0, stream>>>(
        pr2, W2, b2, hh2, NB, NH2, NH1);
    out_kernel<<<dim3(NB / 256), 256, 0, stream>>>(hh2, Wo, bo, (float*)d_out);
}

// Round 3
// 146.463 us; speedup vs baseline: 1.2622x; 1.2622x over previous
//
#include <hip/hip_runtime.h>

// PeerNet: out = relu-MLP with per-feature kNN-mean (k=6, 1D) in the middle.
// B=4096, D=1024, H1=128, H2=64, O=2. All fp32.

#define NB   4096
#define DIN  1024
#define NH1  128
#define NH2  64
#define SPLITK 4          // gemm1 K split: grid 128x4 = 512 blocks = 2/CU

// ---------------------------------------------------------------------------
// GEMM1 (split-K): part[s][n][m] = x[m][k in chunk s] @ W1[n][k]^T
// BM=32, BN=128, BK=16, 256 threads, thread tile 4x4.
// Epilogue bounces the 32x128 tile through LDS for coalesced [n][m] stores.
// ---------------------------------------------------------------------------
__global__ __launch_bounds__(256) void gemm1_kernel(const float* __restrict__ A,
                                                    const float* __restrict__ Bw,
                                                    float* __restrict__ CP)
{
    const int K = DIN;
    const int M = NB;
    __shared__ float As[16 * 36];    // [k][m], pad 36 (16B-aligned rows)
    __shared__ float Bs[16 * 132];   // [k][n]
    __shared__ float Cs[32 * 132];   // [m][n] epilogue bounce
    const int tid = threadIdx.x;
    const int m0  = blockIdx.x * 32;
    const int kb0 = blockIdx.y * (DIN / SPLITK);  // 256-wide K chunk
    const int tr  = tid >> 5;        // 0..7  -> rows 4*tr..4*tr+3
    const int tc  = tid & 31;        // 0..31 -> cols 4*tc..4*tc+3
    const int am  = tid >> 4, ak = tid & 15;
    const int bn  = tid >> 2, bk = (tid & 3) << 2;

    float acc[4][4];
#pragma unroll
    for (int i = 0; i < 4; ++i)
#pragma unroll
        for (int j = 0; j < 4; ++j) acc[i][j] = 0.f;

    for (int k0 = 0; k0 < DIN / SPLITK; k0 += 16) {
        const int kb = kb0 + k0;
        As[ak * 36 + am]      = A[(size_t)(m0 + am) * K + kb + ak];
        As[ak * 36 + am + 16] = A[(size_t)(m0 + am + 16) * K + kb + ak];
        const float4 v0 = *(const float4*)&Bw[(size_t)bn * K + kb + bk];
        const float4 v1 = *(const float4*)&Bw[(size_t)(bn + 64) * K + kb + bk];
        Bs[(bk + 0) * 132 + bn] = v0.x;
        Bs[(bk + 1) * 132 + bn] = v0.y;
        Bs[(bk + 2) * 132 + bn] = v0.z;
        Bs[(bk + 3) * 132 + bn] = v0.w;
        Bs[(bk + 0) * 132 + bn + 64] = v1.x;
        Bs[(bk + 1) * 132 + bn + 64] = v1.y;
        Bs[(bk + 2) * 132 + bn + 64] = v1.z;
        Bs[(bk + 3) * 132 + bn + 64] = v1.w;
        __syncthreads();
#pragma unroll
        for (int k = 0; k < 16; ++k) {
            const float4 a = *(const float4*)&As[k * 36 + 4 * tr];   // broadcast
            const float4 b = *(const float4*)&Bs[k * 132 + 4 * tc];
            const float av[4] = {a.x, a.y, a.z, a.w};
#pragma unroll
            for (int mi = 0; mi < 4; ++mi) {
                acc[mi][0] = fmaf(av[mi], b.x, acc[mi][0]);
                acc[mi][1] = fmaf(av[mi], b.y, acc[mi][1]);
                acc[mi][2] = fmaf(av[mi], b.z, acc[mi][2]);
                acc[mi][3] = fmaf(av[mi], b.w, acc[mi][3]);
            }
        }
        __syncthreads();
    }

    // partial sums -> Cs[m][n] -> coalesced [n][m] store
#pragma unroll
    for (int mi = 0; mi < 4; ++mi)
#pragma unroll
        for (int j = 0; j < 4; ++j)
            Cs[(4 * tr + mi) * 132 + 4 * tc + j] = acc[mi][j];
    __syncthreads();
#pragma unroll
    for (int it = 0; it < 16; ++it) {
        const int idx = it * 256 + tid;
        const int n = idx >> 5, m = idx & 31;
        CP[((size_t)blockIdx.y * NH1 + n) * M + m0 + m] = Cs[m * 132 + n];
    }
}

// ---------------------------------------------------------------------------
// Reduce split-K partials + bias + relu -> h1T[n][m]. Pure streaming, L2-hot.
// ---------------------------------------------------------------------------
__global__ __launch_bounds__(256) void reduce_relu_kernel(const float* __restrict__ P,
                                                          const float* __restrict__ bias,
                                                          float* __restrict__ h1T)
{
    const int i4 = (blockIdx.x * 256 + threadIdx.x) * 4;
    const int n  = i4 >> 12;               // row length NB=4096
    const float4 a = *(const float4*)&P[i4];
    const float4 b = *(const float4*)&P[(size_t)NH1 * NB + i4];
    const float4 c = *(const float4*)&P[(size_t)2 * NH1 * NB + i4];
    const float4 d = *(const float4*)&P[(size_t)3 * NH1 * NB + i4];
    const float bv = bias[n];
    float4 o;
    o.x = fmaxf(a.x + b.x + c.x + d.x + bv, 0.f);
    o.y = fmaxf(a.y + b.y + c.y + d.y + bv, 0.f);
    o.z = fmaxf(a.z + b.z + c.z + d.z + bv, 0.f);
    o.w = fmaxf(a.w + b.w + c.w + d.w + bv, 0.f);
    *(float4*)&h1T[i4] = o;
}

// ---------------------------------------------------------------------------
// kNN stage 1: bitonic-sort each half-column (2048 elems) in LDS.
// grid 256 = 128 cols x 2 halves, 512 threads. All CUs busy.
// ---------------------------------------------------------------------------
__global__ __launch_bounds__(512) void sort_half_kernel(const float* __restrict__ h1T,
                                                        float* __restrict__ sorted)
{
    __shared__ float s[2048];
    const int col  = blockIdx.x >> 1;
    const int half = blockIdx.x & 1;
    const float* __restrict__ src = h1T + (size_t)col * NB + half * 2048;
#pragma unroll
    for (int p = 0; p < 4; ++p) s[threadIdx.x + p * 512] = src[threadIdx.x + p * 512];
    __syncthreads();

    for (int k = 2; k <= 2048; k <<= 1) {
        for (int j = k >> 1; j > 0; j >>= 1) {
#pragma unroll
            for (int p = 0; p < 2; ++p) {
                const int t   = threadIdx.x + p * 512;         // 0..1023 CE index
                const int i   = ((t & ~(j - 1)) << 1) | (t & (j - 1));
                const int ixj = i | j;
                const float a = s[i], b = s[ixj];
                const bool up = ((i & k) == 0);
                if ((a > b) == up) { s[i] = b; s[ixj] = a; }
            }
            __syncthreads();
        }
    }
    float* __restrict__ dst = sorted + (size_t)col * NB + half * 2048;
#pragma unroll
    for (int p = 0; p < 4; ++p) dst[threadIdx.x + p * 512] = s[threadIdx.x + p * 512];
}

// ---------------------------------------------------------------------------
// kNN stage 2: merge the two sorted halves via binary-search ranks (stable:
// lower_bound for half0, upper_bound for half1 -> unique ranks), scatter to
// LDS, then per original element: lower_bound + greedy 6-window mean.
// One block per column, 1024 threads.
// ---------------------------------------------------------------------------
__global__ __launch_bounds__(1024) void knn_merge_kernel(const float* __restrict__ h1T,
                                                         const float* __restrict__ sorted,
                                                         float* __restrict__ prtT)
{
    __shared__ float sin_[NB];
    __shared__ float s[NB];
    const int col = blockIdx.x;
    const float* __restrict__ src = sorted + (size_t)col * NB;
#pragma unroll
    for (int p = 0; p < 4; ++p) sin_[threadIdx.x + p * 1024] = src[threadIdx.x + p * 1024];
    __syncthreads();

#pragma unroll
    for (int p = 0; p < 2; ++p) {
        const int j = threadIdx.x + p * 1024;   // 0..2047
        {   // half0 element: rank = j + #(half1 < v)
            const float v = sin_[j];
            int lo = 0, hi = 2048;
            while (lo < hi) { const int mid = (lo + hi) >> 1; if (sin_[2048 + mid] < v) lo = mid + 1; else hi = mid; }
            s[j + lo] = v;
        }
        {   // half1 element: rank = j + #(half0 <= v)
            const float v = sin_[2048 + j];
            int lo = 0, hi = 2048;
            while (lo < hi) { const int mid = (lo + hi) >> 1; if (sin_[mid] <= v) lo = mid + 1; else hi = mid; }
            s[j + lo] = v;
        }
    }
    __syncthreads();

    const float* __restrict__ colp = h1T + (size_t)col * NB;
#pragma unroll
    for (int p = 0; p < 4; ++p) {
        const int e   = threadIdx.x + p * 1024;
        const float v = colp[e];
        int lo = 0, hi = NB;
        while (lo < hi) {
            const int mid = (lo + hi) >> 1;
            if (s[mid] < v) lo = mid + 1; else hi = mid;
        }
        int l = lo, h = lo;
        float sum = v;  // self
#pragma unroll
        for (int it = 0; it < 5; ++it) {
            const int li = (l > 0) ? l - 1 : 0;
            const int ri = (h < NB - 1) ? h + 1 : NB - 1;
            const float sl = s[li];
            const float sr = s[ri];
            const float dl = (l > 0) ? (v - sl) : 1e30f;
            const float dr = (h < NB - 1) ? (sr - v) : 1e30f;
            if (dl <= dr) { sum += sl; l = li; }
            else          { sum += sr; h = ri; }
        }
        prtT[(size_t)col * NB + e] = sum * (1.0f / 6.0f);
    }
}

// ---------------------------------------------------------------------------
// Generic small GEMM: C[M][N] = relu(A[M][K] @ B[N][K]^T + bias)
// AT=true: A stored transposed as A_T[K][M]. BM=16, BN=64, BK=32, 256 thr.
// ---------------------------------------------------------------------------
template <bool AT>
__global__ __launch_bounds__(256) void gemm_small_kernel(const float* __restrict__ A,
                                                         const float* __restrict__ Bw,
                                                         const float* __restrict__ bias,
                                                         float* __restrict__ C,
                                                         int M, int N, int K)
{
    __shared__ float As[32 * 17];   // [k][m]
    __shared__ float Bs[32 * 68];   // [k][n]
    const int tid = threadIdx.x;
    const int m0 = blockIdx.x * 16;
    const int n0 = blockIdx.y * 64;
    const int r  = tid >> 4;
    const int c0 = (tid & 15) << 2;
    const int bn = tid >> 2, bk = (tid & 3) << 2;
    float acc[4] = {0.f, 0.f, 0.f, 0.f};

    for (int k0 = 0; k0 < K; k0 += 32) {
        if (AT) {
            const int kk = tid >> 4, mm = tid & 15;          // A_T[K][M]
            As[kk * 17 + mm]        = A[(size_t)(k0 + kk) * M + m0 + mm];
            As[(kk + 16) * 17 + mm] = A[(size_t)(k0 + kk + 16) * M + m0 + mm];
        } else {
            const int mm = tid >> 4, kk = tid & 15;          // A[M][K]
            As[kk * 17 + mm]        = A[(size_t)(m0 + mm) * K + k0 + kk];
            As[(kk + 16) * 17 + mm] = A[(size_t)(m0 + mm) * K + k0 + kk + 16];
        }
        const float4 v0 = *(const float4*)&Bw[(size_t)(n0 + bn) * K + k0 + bk];
        const float4 v1 = *(const float4*)&Bw[(size_t)(n0 + bn) * K + k0 + bk + 16];
        Bs[(bk + 0) * 68 + bn] = v0.x;
        Bs[(bk + 1) * 68 + bn] = v0.y;
        Bs[(bk + 2) * 68 + bn] = v0.z;
        Bs[(bk + 3) * 68 + bn] = v0.w;
        Bs[(bk + 16) * 68 + bn] = v1.x;
        Bs[(bk + 17) * 68 + bn] = v1.y;
        Bs[(bk + 18) * 68 + bn] = v1.z;
        Bs[(bk + 19) * 68 + bn] = v1.w;
        __syncthreads();
#pragma unroll
        for (int k = 0; k < 32; ++k) {
            const float a  = As[k * 17 + r];
            const float4 b = *(const float4*)&Bs[k * 68 + c0];
            acc[0] = fmaf(a, b.x, acc[0]);
            acc[1] = fmaf(a, b.y, acc[1]);
            acc[2] = fmaf(a, b.z, acc[2]);
            acc[3] = fmaf(a, b.w, acc[3]);
        }
        __syncthreads();
    }
    const float4 bb = *(const float4*)&bias[n0 + c0];
    float4 o;
    o.x = fmaxf(acc[0] + bb.x, 0.f);
    o.y = fmaxf(acc[1] + bb.y, 0.f);
    o.z = fmaxf(acc[2] + bb.z, 0.f);
    o.w = fmaxf(acc[3] + bb.w, 0.f);
    *(float4*)&C[(size_t)(m0 + r) * N + n0 + c0] = o;
}

// ---------------------------------------------------------------------------
// Final: out[4096][2] = h2[4096][64] @ Wo[2][64]^T + bo  (no relu)
// ---------------------------------------------------------------------------
__global__ __launch_bounds__(256) void out_kernel(const float* __restrict__ h2v,
                                                  const float* __restrict__ Wo,
                                                  const float* __restrict__ bo,
                                                  float* __restrict__ out)
{
    const int row = blockIdx.x * 256 + threadIdx.x;
    const float* __restrict__ hp = h2v + (size_t)row * NH2;
    float a0 = 0.f, a1 = 0.f;
#pragma unroll
    for (int k = 0; k < NH2; k += 4) {
        const float4 h  = *(const float4*)&hp[k];
        const float4 w0 = *(const float4*)&Wo[k];
        const float4 w1 = *(const float4*)&Wo[NH2 + k];
        a0 = fmaf(h.x, w0.x, a0); a0 = fmaf(h.y, w0.y, a0);
        a0 = fmaf(h.z, w0.z, a0); a0 = fmaf(h.w, w0.w, a0);
        a1 = fmaf(h.x, w1.x, a1); a1 = fmaf(h.y, w1.y, a1);
        a1 = fmaf(h.z, w1.z, a1); a1 = fmaf(h.w, w1.w, a1);
    }
    out[row * 2 + 0] = a0 + bo[0];
    out[row * 2 + 1] = a1 + bo[1];
}

extern "C" void kernel_launch(void* const* d_in, const int* in_sizes, int n_in,
                              void* d_out, int out_size, void* d_ws, size_t ws_size,
                              hipStream_t stream)
{
    const float* x   = (const float*)d_in[0];
    const float* W1  = (const float*)d_in[1];
    const float* b1  = (const float*)d_in[2];
    const float* Wpr = (const float*)d_in[3];
    const float* bpr = (const float*)d_in[4];
    const float* W2  = (const float*)d_in[5];
    const float* b2  = (const float*)d_in[6];
    const float* Wo  = (const float*)d_in[7];
    const float* bo  = (const float*)d_in[8];

    float* ws     = (float*)d_ws;
    float* part   = ws;                               // [4][128][4096]  8 MB
    float* h1T    = part + SPLITK * NH1 * NB;         // [128][4096]     2 MB
    float* sorted = h1T + NH1 * NB;                   // [128][4096]     2 MB
    float* prtT   = sorted + NH1 * NB;                // [128][4096]     2 MB
    float* pr2    = prtT + NH1 * NB;                  // [4096][128]     2 MB
    float* hh2    = pr2 + NB * NH1;                   // [4096][64]      1 MB

    gemm1_kernel<<<dim3(NB / 32, SPLITK), 256, 0, stream>>>(x, W1, part);
    reduce_relu_kernel<<<dim3(NH1 * NB / 4 / 256), 256, 0, stream>>>(part, b1, h1T);
    sort_half_kernel<<<dim3(NH1 * 2), 512, 0, stream>>>(h1T, sorted);
    knn_merge_kernel<<<dim3(NH1), 1024, 0, stream>>>(h1T, sorted, prtT);
    gemm_small_kernel<true><<<dim3(NB / 16, NH1 / 64), 256, 0, stream>>>(
        prtT, Wpr, bpr, pr2, NB, NH1, NH1);
    gemm_small_kernel<false><<<dim3(NB / 16, NH2 / 64), 256, 0, stream>>>(
        pr2, W2, b2, hh2, NB, NH2, NH1);
    out_kernel<<<dim3(NB / 256), 256, 0, stream>>>(hh2, Wo, bo, (float*)d_out);
}

// Round 4
// 132.919 us; speedup vs baseline: 1.3908x; 1.1019x over previous
//
#include <hip/hip_runtime.h>

// PeerNet: out = relu-MLP with per-feature kNN-mean (k=6, 1D) in the middle.
// B=4096, D=1024, H1=128, H2=64, O=2. All fp32.

#define NB   4096
#define DIN  1024
#define NH1  128
#define NH2  64
#define SPLITK 4          // gemm1 K split: grid 128x4 = 512 blocks = 2/CU

// ---------------------------------------------------------------------------
// GEMM1 (split-K): part[s][n][m] = x[m][k in chunk s] @ W1[n][k]^T
// BM=32, BN=128, BK=16, 256 threads, thread tile 4x4.
// ---------------------------------------------------------------------------
__global__ __launch_bounds__(256) void gemm1_kernel(const float* __restrict__ A,
                                                    const float* __restrict__ Bw,
                                                    float* __restrict__ CP)
{
    const int K = DIN;
    const int M = NB;
    __shared__ float As[16 * 36];
    __shared__ float Bs[16 * 132];
    __shared__ float Cs[32 * 132];
    const int tid = threadIdx.x;
    const int m0  = blockIdx.x * 32;
    const int kb0 = blockIdx.y * (DIN / SPLITK);
    const int tr  = tid >> 5;
    const int tc  = tid & 31;
    const int am  = tid >> 4, ak = tid & 15;
    const int bn  = tid >> 2, bk = (tid & 3) << 2;

    float acc[4][4];
#pragma unroll
    for (int i = 0; i < 4; ++i)
#pragma unroll
        for (int j = 0; j < 4; ++j) acc[i][j] = 0.f;

    for (int k0 = 0; k0 < DIN / SPLITK; k0 += 16) {
        const int kb = kb0 + k0;
        As[ak * 36 + am]      = A[(size_t)(m0 + am) * K + kb + ak];
        As[ak * 36 + am + 16] = A[(size_t)(m0 + am + 16) * K + kb + ak];
        const float4 v0 = *(const float4*)&Bw[(size_t)bn * K + kb + bk];
        const float4 v1 = *(const float4*)&Bw[(size_t)(bn + 64) * K + kb + bk];
        Bs[(bk + 0) * 132 + bn] = v0.x;
        Bs[(bk + 1) * 132 + bn] = v0.y;
        Bs[(bk + 2) * 132 + bn] = v0.z;
        Bs[(bk + 3) * 132 + bn] = v0.w;
        Bs[(bk + 0) * 132 + bn + 64] = v1.x;
        Bs[(bk + 1) * 132 + bn + 64] = v1.y;
        Bs[(bk + 2) * 132 + bn + 64] = v1.z;
        Bs[(bk + 3) * 132 + bn + 64] = v1.w;
        __syncthreads();
#pragma unroll
        for (int k = 0; k < 16; ++k) {
            const float4 a = *(const float4*)&As[k * 36 + 4 * tr];
            const float4 b = *(const float4*)&Bs[k * 132 + 4 * tc];
            const float av[4] = {a.x, a.y, a.z, a.w};
#pragma unroll
            for (int mi = 0; mi < 4; ++mi) {
                acc[mi][0] = fmaf(av[mi], b.x, acc[mi][0]);
                acc[mi][1] = fmaf(av[mi], b.y, acc[mi][1]);
                acc[mi][2] = fmaf(av[mi], b.z, acc[mi][2]);
                acc[mi][3] = fmaf(av[mi], b.w, acc[mi][3]);
            }
        }
        __syncthreads();
    }

#pragma unroll
    for (int mi = 0; mi < 4; ++mi)
#pragma unroll
        for (int j = 0; j < 4; ++j)
            Cs[(4 * tr + mi) * 132 + 4 * tc + j] = acc[mi][j];
    __syncthreads();
#pragma unroll
    for (int it = 0; it < 16; ++it) {
        const int idx = it * 256 + tid;
        const int n = idx >> 5, m = idx & 31;
        CP[((size_t)blockIdx.y * NH1 + n) * M + m0 + m] = Cs[m * 132 + n];
    }
}

// ---------------------------------------------------------------------------
// Reduce split-K partials + bias + relu -> h1T[n][m].
// ---------------------------------------------------------------------------
__global__ __launch_bounds__(256) void reduce_relu_kernel(const float* __restrict__ P,
                                                          const float* __restrict__ bias,
                                                          float* __restrict__ h1T)
{
    const int i4 = (blockIdx.x * 256 + threadIdx.x) * 4;
    const int n  = i4 >> 12;
    const float4 a = *(const float4*)&P[i4];
    const float4 b = *(const float4*)&P[(size_t)NH1 * NB + i4];
    const float4 c = *(const float4*)&P[(size_t)2 * NH1 * NB + i4];
    const float4 d = *(const float4*)&P[(size_t)3 * NH1 * NB + i4];
    const float bv = bias[n];
    float4 o;
    o.x = fmaxf(a.x + b.x + c.x + d.x + bv, 0.f);
    o.y = fmaxf(a.y + b.y + c.y + d.y + bv, 0.f);
    o.z = fmaxf(a.z + b.z + c.z + d.z + bv, 0.f);
    o.w = fmaxf(a.w + b.w + c.w + d.w + bv, 0.f);
    *(float4*)&h1T[i4] = o;
}

// ---------------------------------------------------------------------------
// kNN stage 1: bitonic-sort each half-column (2048) — hybrid LDS/shuffle.
// All CE stages with j<=32 run in-register via __shfl_xor (pairs stay inside
// one 64-lane wave); only j>=64 stages touch LDS. grid 256, 512 threads.
// Thread t holds elements i = t + q*512, q=0..3 (contiguous 64-blocks per
// wave since t = w*64+lane).
// ---------------------------------------------------------------------------
__global__ __launch_bounds__(512) void sort_half_kernel(const float* __restrict__ h1T,
                                                        float* __restrict__ sorted)
{
    __shared__ float s[2048];
    const int t = threadIdx.x;
    const int col  = blockIdx.x >> 1;
    const int half = blockIdx.x & 1;
    const float* __restrict__ src = h1T + (size_t)col * NB + half * 2048;

    float v[4];
#pragma unroll
    for (int q = 0; q < 4; ++q) v[q] = src[t + q * 512];

    // k = 2..64 entirely in registers (0 barriers)
#pragma unroll
    for (int k = 2; k <= 64; k <<= 1) {
#pragma unroll
        for (int j = k >> 1; j > 0; j >>= 1) {
#pragma unroll
            for (int q = 0; q < 4; ++q) {
                const int i = q * 512 + t;
                const float p = __shfl_xor(v[q], j);
                const bool up  = ((i & k) == 0);
                const bool low = ((i & j) == 0);
                v[q] = (low == up) ? fminf(v[q], p) : fmaxf(v[q], p);
            }
        }
    }
#pragma unroll
    for (int q = 0; q < 4; ++q) s[t + q * 512] = v[q];
    __syncthreads();

    for (int k = 128; k <= 2048; k <<= 1) {
        for (int j = k >> 1; j >= 64; j >>= 1) {
#pragma unroll
            for (int p = 0; p < 2; ++p) {
                const int c = t + p * 512;
                const int i = ((c & ~(j - 1)) << 1) | (c & (j - 1));
                const int ixj = i | j;
                const float a = s[i], b = s[ixj];
                const bool up = ((i & k) == 0);
                if ((a > b) == up) { s[i] = b; s[ixj] = a; }
            }
            __syncthreads();
        }
        // j = 32..1 in registers
#pragma unroll
        for (int q = 0; q < 4; ++q) v[q] = s[t + q * 512];
#pragma unroll
        for (int j = 32; j > 0; j >>= 1) {
#pragma unroll
            for (int q = 0; q < 4; ++q) {
                const int i = q * 512 + t;
                const float p = __shfl_xor(v[q], j);
                const bool up  = ((i & k) == 0);
                const bool low = ((i & j) == 0);
                v[q] = (low == up) ? fminf(v[q], p) : fmaxf(v[q], p);
            }
        }
#pragma unroll
        for (int q = 0; q < 4; ++q) s[t + q * 512] = v[q];
        __syncthreads();
    }

    float* __restrict__ dst = sorted + (size_t)col * NB + half * 2048;
#pragma unroll
    for (int q = 0; q < 4; ++q) dst[t + q * 512] = s[t + q * 512];
}

// ---------------------------------------------------------------------------
// kNN stage 2: 2 blocks per column (grid 256). Each block re-merges the two
// sorted halves via binary-search ranks (stable), then runs the 6-window
// phase on ITS half of the original elements (2/thread).
// ---------------------------------------------------------------------------
__global__ __launch_bounds__(1024) void knn_merge_kernel(const float* __restrict__ h1T,
                                                         const float* __restrict__ sorted,
                                                         float* __restrict__ prtT)
{
    __shared__ float sin_[NB];
    __shared__ float s[NB];
    const int col  = blockIdx.x >> 1;
    const int half = blockIdx.x & 1;
    const float* __restrict__ src = sorted + (size_t)col * NB;
#pragma unroll
    for (int p = 0; p < 4; ++p) sin_[threadIdx.x + p * 1024] = src[threadIdx.x + p * 1024];
    __syncthreads();

#pragma unroll
    for (int p = 0; p < 2; ++p) {
        const int j = threadIdx.x + p * 1024;   // 0..2047
        {   // half0 element: rank = j + #(half1 < v)
            const float v = sin_[j];
            int lo = 0, hi = 2048;
            while (lo < hi) { const int mid = (lo + hi) >> 1; if (sin_[2048 + mid] < v) lo = mid + 1; else hi = mid; }
            s[j + lo] = v;
        }
        {   // half1 element: rank = j + #(half0 <= v)
            const float v = sin_[2048 + j];
            int lo = 0, hi = 2048;
            while (lo < hi) { const int mid = (lo + hi) >> 1; if (sin_[mid] <= v) lo = mid + 1; else hi = mid; }
            s[j + lo] = v;
        }
    }
    __syncthreads();

    const float* __restrict__ colp = h1T + (size_t)col * NB;
#pragma unroll
    for (int p = 0; p < 2; ++p) {
        const int e   = half * 2048 + threadIdx.x + p * 1024;
        const float v = colp[e];
        int lo = 0, hi = NB;
        while (lo < hi) {
            const int mid = (lo + hi) >> 1;
            if (s[mid] < v) lo = mid + 1; else hi = mid;
        }
        int l = lo, h = lo;
        float sum = v;  // self
#pragma unroll
        for (int it = 0; it < 5; ++it) {
            const int li = (l > 0) ? l - 1 : 0;
            const int ri = (h < NB - 1) ? h + 1 : NB - 1;
            const float sl = s[li];
            const float sr = s[ri];
            const float dl = (l > 0) ? (v - sl) : 1e30f;
            const float dr = (h < NB - 1) ? (sr - v) : 1e30f;
            if (dl <= dr) { sum += sl; l = li; }
            else          { sum += sr; h = ri; }
        }
        prtT[(size_t)col * NB + e] = sum * (1.0f / 6.0f);
    }
}

// ---------------------------------------------------------------------------
// Fused tail: out = (relu(relu(prT^T @ Wpr^T + bpr) @ W2^T + b2)) @ Wo^T + bo
// Grid 256 blocks x 16 rows, 256 threads. Weights staged in LDS chunks;
// pr tile lives in LDS between the two GEMMs; Wo dot reduced via LDS.
// ---------------------------------------------------------------------------
__global__ __launch_bounds__(256) void tail_kernel(const float* __restrict__ AT,
                                                   const float* __restrict__ Wpr,
                                                   const float* __restrict__ bpr,
                                                   const float* __restrict__ W2,
                                                   const float* __restrict__ b2,
                                                   const float* __restrict__ Wo,
                                                   const float* __restrict__ bo,
                                                   float* __restrict__ out)
{
    __shared__ float As[NH1 * 17];   // A^T tile [k=128][m=16]
    __shared__ float Bs[32 * 132];   // weight chunk staging (transposed)
    __shared__ float Ps[16 * 132];   // pr tile [m][n=128]
    __shared__ float Rs[16 * 32];    // out reduction [g][m*2+o]
    const int tid = threadIdx.x;
    const int m0  = blockIdx.x * 16;

    // load A tile: As[k][m] = AT[k*NB + m0 + m]; 512 float4, 2/thread
    {
        const int row = tid >> 2;
        const int f   = (tid & 3) * 4;
#pragma unroll
        for (int h = 0; h < 2; ++h) {
            const int k = row + h * 64;
            const float4 v = *(const float4*)&AT[(size_t)k * NB + m0 + f];
            As[k * 17 + f + 0] = v.x;
            As[k * 17 + f + 1] = v.y;
            As[k * 17 + f + 2] = v.z;
            As[k * 17 + f + 3] = v.w;
        }
    }

    const int m  = tid & 15;
    const int g  = tid >> 4;     // 0..15
    const int n0 = g * 8;

    float acc[8];
#pragma unroll
    for (int j = 0; j < 8; ++j) acc[j] = 0.f;

    for (int k0 = 0; k0 < NH1; k0 += 32) {
        {   // Bs[kk][n] = Wpr[n][k0+kk]
            const int n  = tid >> 1;
            const int ko = (tid & 1) * 16;
#pragma unroll
            for (int i4 = 0; i4 < 4; ++i4) {
                const float4 v = *(const float4*)&Wpr[(size_t)n * NH1 + k0 + ko + i4 * 4];
                Bs[(ko + i4 * 4 + 0) * 132 + n] = v.x;
                Bs[(ko + i4 * 4 + 1) * 132 + n] = v.y;
                Bs[(ko + i4 * 4 + 2) * 132 + n] = v.z;
                Bs[(ko + i4 * 4 + 3) * 132 + n] = v.w;
            }
        }
        __syncthreads();
#pragma unroll
        for (int kk = 0; kk < 32; ++kk) {
            const float a   = As[(k0 + kk) * 17 + m];
            const float4 b0 = *(const float4*)&Bs[kk * 132 + n0];
            const float4 b1 = *(const float4*)&Bs[kk * 132 + n0 + 4];
            acc[0] = fmaf(a, b0.x, acc[0]);
            acc[1] = fmaf(a, b0.y, acc[1]);
            acc[2] = fmaf(a, b0.z, acc[2]);
            acc[3] = fmaf(a, b0.w, acc[3]);
            acc[4] = fmaf(a, b1.x, acc[4]);
            acc[5] = fmaf(a, b1.y, acc[5]);
            acc[6] = fmaf(a, b1.z, acc[6]);
            acc[7] = fmaf(a, b1.w, acc[7]);
        }
        __syncthreads();
    }
#pragma unroll
    for (int j = 0; j < 8; ++j)
        Ps[m * 132 + n0 + j] = fmaxf(acc[j] + bpr[n0 + j], 0.f);
    __syncthreads();

    // GEMM B: h2[m][j2], 4 per thread (j0 = g*4), reduce over n=0..127
    const int j0 = g * 4;
    float acc2[4] = {0.f, 0.f, 0.f, 0.f};
    for (int n0c = 0; n0c < NH1; n0c += 32) {
        {   // Bs2[nn][j2] = W2[j2][n0c+nn] (stride 68)
            const int j2 = tid >> 2;
            const int no = (tid & 3) * 8;
#pragma unroll
            for (int i4 = 0; i4 < 2; ++i4) {
                const float4 v = *(const float4*)&W2[(size_t)j2 * NH1 + n0c + no + i4 * 4];
                Bs[(no + i4 * 4 + 0) * 68 + j2] = v.x;
                Bs[(no + i4 * 4 + 1) * 68 + j2] = v.y;
                Bs[(no + i4 * 4 + 2) * 68 + j2] = v.z;
                Bs[(no + i4 * 4 + 3) * 68 + j2] = v.w;
            }
        }
        __syncthreads();
#pragma unroll
        for (int nn = 0; nn < 32; ++nn) {
            const float p  = Ps[m * 132 + n0c + nn];
            const float4 w = *(const float4*)&Bs[nn * 68 + j0];
            acc2[0] = fmaf(p, w.x, acc2[0]);
            acc2[1] = fmaf(p, w.y, acc2[1]);
            acc2[2] = fmaf(p, w.z, acc2[2]);
            acc2[3] = fmaf(p, w.w, acc2[3]);
        }
        __syncthreads();
    }

    float po0 = 0.f, po1 = 0.f;
#pragma unroll
    for (int j = 0; j < 4; ++j) {
        const float h = fmaxf(acc2[j] + b2[j0 + j], 0.f);
        po0 = fmaf(h, Wo[j0 + j], po0);
        po1 = fmaf(h, Wo[NH2 + j0 + j], po1);
    }
    Rs[g * 32 + m * 2 + 0] = po0;
    Rs[g * 32 + m * 2 + 1] = po1;
    __syncthreads();
    if (tid < 32) {
        const int mm = tid >> 1, o = tid & 1;
        float sum = 0.f;
#pragma unroll
        for (int gg = 0; gg < 16; ++gg) sum += Rs[gg * 32 + mm * 2 + o];
        out[(size_t)(m0 + mm) * 2 + o] = sum + bo[o];
    }
}

extern "C" void kernel_launch(void* const* d_in, const int* in_sizes, int n_in,
                              void* d_out, int out_size, void* d_ws, size_t ws_size,
                              hipStream_t stream)
{
    const float* x   = (const float*)d_in[0];
    const float* W1  = (const float*)d_in[1];
    const float* b1  = (const float*)d_in[2];
    const float* Wpr = (const float*)d_in[3];
    const float* bpr = (const float*)d_in[4];
    const float* W2  = (const float*)d_in[5];
    const float* b2  = (const float*)d_in[6];
    const float* Wo  = (const float*)d_in[7];
    const float* bo  = (const float*)d_in[8];

    float* ws     = (float*)d_ws;
    float* part   = ws;                               // [4][128][4096]  8 MB
    float* h1T    = part + SPLITK * NH1 * NB;         // [128][4096]     2 MB
    float* sorted = h1T + NH1 * NB;                   // [128][4096]     2 MB
    float* prtT   = sorted + NH1 * NB;                // [128][4096]     2 MB

    gemm1_kernel<<<dim3(NB / 32, SPLITK), 256, 0, stream>>>(x, W1, part);
    reduce_relu_kernel<<<dim3(NH1 * NB / 4 / 256), 256, 0, stream>>>(part, b1, h1T);
    sort_half_kernel<<<dim3(NH1 * 2), 512, 0, stream>>>(h1T, sorted);
    knn_merge_kernel<<<dim3(NH1 * 2), 1024, 0, stream>>>(h1T, sorted, prtT);
    tail_kernel<<<dim3(NB / 16), 256, 0, stream>>>(prtT, Wpr, bpr, W2, b2, Wo, bo,
                                                   (float*)d_out);
}